// Round 1
// baseline (435.759 us; speedup 1.0000x reference)
//
#include <hip/hip_runtime.h>
#include <hip/hip_bf16.h>
#include <stdint.h>

#define IN_F 4096
#define OUT_F 4096
#define GS 128
#define M_TOTAL 8192   // 4 * 2048

typedef __hip_bfloat16 bf16;
typedef __attribute__((ext_vector_type(8))) short bf16x8;   // 8 bf16 (4 VGPRs)
typedef __attribute__((ext_vector_type(4))) float f32x4;    // MFMA accumulator

// ---------------- kernel 1: dequant packed int4 -> bf16 W (OUT_F x IN_F, row-major, K-contiguous)
__global__ __launch_bounds__(256) void dequant_w(const int* __restrict__ qweight,
                                                 const float* __restrict__ scales,
                                                 const int* __restrict__ qzeros,
                                                 bf16* __restrict__ Wb) {
    int idx = blockIdx.x * 256 + threadIdx.x;       // one int32 (8 nibbles) per thread
    int o = idx >> 9;                               // / (IN_F/8)
    int j = idx & 511;
    int g = j >> 4;                                 // (j*8)/GS
    int qw = qweight[idx];
    float s = scales[g * OUT_F + o];
    float z = (float)qzeros[g * OUT_F + o];
    union { bf16 h[8]; uint4 q; } out;
#pragma unroll
    for (int b = 0; b < 8; ++b) {
        float w = (float)((qw >> (4 * b)) & 15);
        out.h[b] = __float2bfloat16((w - z) * s);
    }
    *reinterpret_cast<uint4*>(Wb + ((size_t)o * IN_F + j * 8)) = out.q;
}

// ---------------- kernel 2: x fp32 -> bf16 (vectorized, 8 elems/thread)
__global__ __launch_bounds__(256) void cvt_x(const float* __restrict__ x,
                                             bf16* __restrict__ Xb, int n8) {
    int idx = blockIdx.x * 256 + threadIdx.x;
    if (idx >= n8) return;
    const float4* p = reinterpret_cast<const float4*>(x) + (size_t)idx * 2;
    float4 a = p[0], b = p[1];
    union { bf16 h[8]; uint4 q; } o;
    o.h[0] = __float2bfloat16(a.x); o.h[1] = __float2bfloat16(a.y);
    o.h[2] = __float2bfloat16(a.z); o.h[3] = __float2bfloat16(a.w);
    o.h[4] = __float2bfloat16(b.x); o.h[5] = __float2bfloat16(b.y);
    o.h[6] = __float2bfloat16(b.z); o.h[7] = __float2bfloat16(b.w);
    reinterpret_cast<uint4*>(Xb)[idx] = o.q;
}

// ---------------- kernel 3: bf16 GEMM, C = A(MxK) * B(NxK)^T + bias, m97 structure
#define BM 128
#define BN 128
#define BK 64

__device__ inline void gload16(const bf16* g, bf16* l) {
    __builtin_amdgcn_global_load_lds(
        (const __attribute__((address_space(1))) void*)g,
        (__attribute__((address_space(3))) void*)l, 16, 0, 0);
}

__global__ __launch_bounds__(256) void gemm_bt(const bf16* __restrict__ A,   // M x K
                                               const bf16* __restrict__ B,   // N x K
                                               const float* __restrict__ bias,
                                               float* __restrict__ C) {
    __shared__ bf16 As[BM * BK];   // [128][64], rows of 128B, linear (global_load_lds dest)
    __shared__ bf16 Bs[BN * BK];

    // XCD-aware bijective swizzle: nwg = 2048, divisible by 8
    int nwg = gridDim.x;
    int cpx = nwg >> 3;
    int wg  = blockIdx.x;
    int swz = (wg & 7) * cpx + (wg >> 3);
    int bm  = swz >> 5;          // 32 n-tiles per m-row
    int bn  = swz & 31;

    const int tid  = threadIdx.x;
    const int wave = tid >> 6;
    const int lane = tid & 63;
    const int wr   = wave >> 1;   // 2x2 wave grid, each wave owns 64x64
    const int wc   = wave & 1;

    const int m0 = bm * BM;
    const int n0 = bn * BN;

    f32x4 acc[4][4];
#pragma unroll
    for (int i = 0; i < 4; ++i)
#pragma unroll
        for (int j = 0; j < 4; ++j) acc[i][j] = (f32x4){0.f, 0.f, 0.f, 0.f};

    const int srow = lane >> 3;        // row within 8-row chunk
    const int scol = (lane & 7) * 8;   // element offset within 64-elem row

    for (int kt = 0; kt < IN_F; kt += BK) {
        // stage A and B tiles: 16 chunks of 8 rows x 128B each; wave w does chunks 4w..4w+3
#pragma unroll
        for (int i = 0; i < 4; ++i) {
            int ch = wave * 4 + i;
            int r  = ch * 8 + srow;
            gload16(A + (size_t)(m0 + r) * IN_F + kt + scol, As + ch * 512);
            gload16(B + (size_t)(n0 + r) * IN_F + kt + scol, Bs + ch * 512);
        }
        __syncthreads();   // drains vmcnt before barrier (m97 pattern)

#pragma unroll
        for (int ks = 0; ks < 2; ++ks) {
            bf16x8 af[4], bfr[4];
#pragma unroll
            for (int i = 0; i < 4; ++i) {
                int ar = wr * 64 + i * 16 + (lane & 15);
                af[i]  = *reinterpret_cast<const bf16x8*>(As + ar * BK + ks * 32 + (lane >> 4) * 8);
                int br = wc * 64 + i * 16 + (lane & 15);
                bfr[i] = *reinterpret_cast<const bf16x8*>(Bs + br * BK + ks * 32 + (lane >> 4) * 8);
            }
#pragma unroll
            for (int i = 0; i < 4; ++i)
#pragma unroll
                for (int j = 0; j < 4; ++j)
                    acc[i][j] = __builtin_amdgcn_mfma_f32_16x16x32_bf16(af[i], bfr[j], acc[i][j], 0, 0, 0);
        }
        __syncthreads();
    }

    // epilogue: C/D layout col = lane&15, row = (lane>>4)*4 + reg  [m89/m91 verified]
    const int crow = m0 + wr * 64 + (lane >> 4) * 4;
    const int ccol = n0 + wc * 64 + (lane & 15);
#pragma unroll
    for (int j = 0; j < 4; ++j) {
        float bv = bias[ccol + j * 16];
#pragma unroll
        for (int i = 0; i < 4; ++i)
#pragma unroll
            for (int r = 0; r < 4; ++r)
                C[(size_t)(crow + i * 16 + r) * OUT_F + ccol + j * 16] = acc[i][j][r] + bv;
    }
}

// ---------------- fallback: fp32 tiled GEMM with on-the-fly dequant (only if ws too small)
__global__ __launch_bounds__(256) void fallback_gemm(const float* __restrict__ x,
                                                     const int* __restrict__ qweight,
                                                     const float* __restrict__ scales,
                                                     const int* __restrict__ qzeros,
                                                     const float* __restrict__ bias,
                                                     float* __restrict__ out) {
    __shared__ float Asf[64][65];
    __shared__ float Bsf[64][65];
    int bm = blockIdx.x >> 6;     // 64 n-tiles
    int bn = blockIdx.x & 63;
    int m0 = bm * 64, n0 = bn * 64;
    int t  = threadIdx.x;
    int tr = t >> 4, tc = t & 15;
    float acc[4][4] = {};
    for (int kt = 0; kt < IN_F; kt += 64) {
#pragma unroll
        for (int i = 0; i < 4; ++i) {
            int idx = t + i * 256;            // 1024 float4 slots
            int r = idx >> 4, c4 = idx & 15;
            float4 v = *reinterpret_cast<const float4*>(x + (size_t)(m0 + r) * IN_F + kt + c4 * 4);
            Asf[r][c4 * 4 + 0] = v.x; Asf[r][c4 * 4 + 1] = v.y;
            Asf[r][c4 * 4 + 2] = v.z; Asf[r][c4 * 4 + 3] = v.w;
        }
#pragma unroll
        for (int i = 0; i < 2; ++i) {
            int idx = t + i * 256;            // 512 int32 slots
            int r = idx >> 3, k8 = idx & 7;
            int kk = kt + k8 * 8;
            int o  = n0 + r;
            int qw = qweight[(size_t)o * (IN_F / 8) + (kk >> 3)];
            int g  = kk >> 7;
            float s = scales[g * OUT_F + o];
            float z = (float)qzeros[g * OUT_F + o];
#pragma unroll
            for (int b = 0; b < 8; ++b)
                Bsf[r][k8 * 8 + b] = ((float)((qw >> (4 * b)) & 15) - z) * s;
        }
        __syncthreads();
#pragma unroll 8
        for (int k = 0; k < 64; ++k) {
            float a[4], bb[4];
#pragma unroll
            for (int i = 0; i < 4; ++i) a[i] = Asf[tr * 4 + i][k];
#pragma unroll
            for (int j = 0; j < 4; ++j) bb[j] = Bsf[tc * 4 + j][k];
#pragma unroll
            for (int i = 0; i < 4; ++i)
#pragma unroll
                for (int j = 0; j < 4; ++j) acc[i][j] += a[i] * bb[j];
        }
        __syncthreads();
    }
#pragma unroll
    for (int i = 0; i < 4; ++i) {
        int row = m0 + tr * 4 + i;
#pragma unroll
        for (int j = 0; j < 4; ++j) {
            int col = n0 + tc * 4 + j;
            out[(size_t)row * OUT_F + col] = acc[i][j] + bias[col];
        }
    }
}

extern "C" void kernel_launch(void* const* d_in, const int* in_sizes, int n_in,
                              void* d_out, int out_size, void* d_ws, size_t ws_size,
                              hipStream_t stream) {
    (void)in_sizes; (void)n_in; (void)out_size;
    const float* x       = (const float*)d_in[0];
    const int*   qweight = (const int*)d_in[1];
    const float* scales  = (const float*)d_in[2];
    const int*   qzeros  = (const int*)d_in[3];
    const float* bias    = (const float*)d_in[4];
    float* out = (float*)d_out;

    const size_t needW = (size_t)OUT_F * IN_F * sizeof(bf16);   // 32 MB
    const size_t needX = (size_t)M_TOTAL * IN_F * sizeof(bf16); // 64 MB

    if (ws_size >= needW + needX) {
        bf16* Wb = (bf16*)d_ws;
        bf16* Xb = (bf16*)((char*)d_ws + needW);
        dequant_w<<<(OUT_F * (IN_F / 8)) / 256, 256, 0, stream>>>(qweight, scales, qzeros, Wb);
        int n8 = M_TOTAL * IN_F / 8;
        cvt_x<<<(n8 + 255) / 256, 256, 0, stream>>>(x, Xb, n8);
        gemm_bt<<<(M_TOTAL / BM) * (OUT_F / BN), 256, 0, stream>>>(Xb, Wb, bias, out);
    } else {
        fallback_gemm<<<(M_TOTAL / 64) * (OUT_F / 64), 256, 0, stream>>>(
            x, qweight, scales, qzeros, bias, out);
    }
}

// Round 2
// 274.280 us; speedup vs baseline: 1.5887x; 1.5887x over previous
//
#include <hip/hip_runtime.h>
#include <hip/hip_bf16.h>
#include <stdint.h>

#define IN_F 4096
#define OUT_F 4096
#define M_TOTAL 8192   // 4 * 2048
#define NKT 64         // IN_F / BK

typedef __hip_bfloat16 bf16;
typedef __attribute__((ext_vector_type(8))) short bf16x8;   // 8 bf16 (4 VGPRs)
typedef __attribute__((ext_vector_type(4))) float f32x4;    // MFMA accumulator

// ---------------- kernel 1: dequant packed int4 -> bf16 W (OUT_F x IN_F row-major)
__global__ __launch_bounds__(256) void dequant_w(const int* __restrict__ qweight,
                                                 const float* __restrict__ scales,
                                                 const int* __restrict__ qzeros,
                                                 bf16* __restrict__ Wb) {
    int idx = blockIdx.x * 256 + threadIdx.x;       // one int32 (8 nibbles) per thread
    int o = idx >> 9;                               // / (IN_F/8)
    int j = idx & 511;
    int g = j >> 4;                                 // (j*8)/128
    int qw = qweight[idx];
    float s = scales[g * OUT_F + o];
    float z = (float)qzeros[g * OUT_F + o];
    union { bf16 h[8]; uint4 q; } out;
#pragma unroll
    for (int b = 0; b < 8; ++b) {
        float w = (float)((qw >> (4 * b)) & 15);
        out.h[b] = __float2bfloat16((w - z) * s);
    }
    *reinterpret_cast<uint4*>(Wb + ((size_t)o * IN_F + j * 8)) = out.q;
}

// ---------------- kernel 2: x fp32 -> bf16 (8 elems/thread)
__global__ __launch_bounds__(256) void cvt_x(const float* __restrict__ x,
                                             bf16* __restrict__ Xb, int n8) {
    int idx = blockIdx.x * 256 + threadIdx.x;
    if (idx >= n8) return;
    const float4* p = reinterpret_cast<const float4*>(x) + (size_t)idx * 2;
    float4 a = p[0], b = p[1];
    union { bf16 h[8]; uint4 q; } o;
    o.h[0] = __float2bfloat16(a.x); o.h[1] = __float2bfloat16(a.y);
    o.h[2] = __float2bfloat16(a.z); o.h[3] = __float2bfloat16(a.w);
    o.h[4] = __float2bfloat16(b.x); o.h[5] = __float2bfloat16(b.y);
    o.h[6] = __float2bfloat16(b.z); o.h[7] = __float2bfloat16(b.w);
    reinterpret_cast<uint4*>(Xb)[idx] = o.q;
}

// ---------------- kernel 3: 256x256 8-phase bf16 GEMM (m201 template, plain HIP)
// C(M x N) = A(M x K) * B(N x K)^T + bias.  8 waves (2M x 4N), per-wave 128x64 out.
// LDS 128 KiB: buf b at b*65536; A halves @ +0/+16384, B halves @ +32768/+49152.
// Swizzle: 16B slot s stored at s ^ (row & 7) (involution; applied on global src
// for global_load_lds and on ds_read addresses).

__device__ __forceinline__ void gload16(const bf16* g, char* l) {
    __builtin_amdgcn_global_load_lds(
        (const __attribute__((address_space(1))) void*)g,
        (__attribute__((address_space(3))) void*)l, 16, 0, 0);
}

// Stage 128 rows x 64 cols bf16 (16 KiB): 8 waves x 2 loads x 64 lanes x 16 B.
// Gt points at (row0, k-col0) of the half-tile in global. Row stride = IN_F.
__device__ __forceinline__ void stage_half(const bf16* __restrict__ Gt,
                                           char* ldsb, int wave, int lane) {
    const int slog8 = ((lane & 7) ^ (lane >> 3)) * 8;   // swizzled 16B-slot, bf16 units
#pragma unroll
    for (int j = 0; j < 2; ++j) {
        int r = wave * 16 + j * 8 + (lane >> 3);        // r & 7 == lane>>3
        gload16(Gt + (size_t)r * IN_F + slog8, ldsb + (wave * 2 + j) * 1024);
    }
}

#define BARRIER() do { asm volatile("" ::: "memory"); \
                       __builtin_amdgcn_s_barrier();  \
                       asm volatile("" ::: "memory"); } while (0)
#define LGKM0()   asm volatile("s_waitcnt lgkmcnt(0)" ::: "memory")
#define VMCNT4()  asm volatile("s_waitcnt vmcnt(4)" ::: "memory")
#define VMCNT0()  asm volatile("s_waitcnt vmcnt(0)" ::: "memory")

#define LDA_SET(DST, BUF, MH) do {                                              \
  _Pragma("unroll") for (int m4 = 0; m4 < 4; ++m4)                              \
  _Pragma("unroll") for (int kk = 0; kk < 2; ++kk)                              \
    DST[m4][kk] = *reinterpret_cast<const bf16x8*>(sm + (BUF) * 65536           \
        + ((wr * 128 + (MH) * 64 + m4 * 16 + l15) << 7)                         \
        + ((((kk << 2) + lq) ^ l7) << 4));                                      \
} while (0)

#define LDB_SET(BUF, NH) do {                                                   \
  _Pragma("unroll") for (int n2 = 0; n2 < 2; ++n2)                              \
  _Pragma("unroll") for (int kk = 0; kk < 2; ++kk)                              \
    bfr[n2][kk] = *reinterpret_cast<const bf16x8*>(sm + (BUF) * 65536 + 32768   \
        + ((wc * 64 + (NH) * 32 + n2 * 16 + l15) << 7)                          \
        + ((((kk << 2) + lq) ^ l7) << 4));                                      \
} while (0)

#define MMA_Q(AF, MH, NH) do {                                                  \
  __builtin_amdgcn_s_setprio(1);                                                \
  _Pragma("unroll") for (int m4 = 0; m4 < 4; ++m4)                              \
  _Pragma("unroll") for (int n2 = 0; n2 < 2; ++n2)                              \
  _Pragma("unroll") for (int kk = 0; kk < 2; ++kk)                              \
    acc[(MH) * 4 + m4][(NH) * 2 + n2] = __builtin_amdgcn_mfma_f32_16x16x32_bf16(\
        AF[m4][kk], bfr[n2][kk], acc[(MH) * 4 + m4][(NH) * 2 + n2], 0, 0, 0);   \
  __builtin_amdgcn_s_setprio(0);                                                \
} while (0)

__global__ __launch_bounds__(512, 2) void gemm256(const bf16* __restrict__ A,   // M x K
                                                  const bf16* __restrict__ B,   // N x K
                                                  const float* __restrict__ bias,
                                                  float* __restrict__ C) {
    extern __shared__ char sm[];
    const int tid  = threadIdx.x;
    const int wave = tid >> 6;
    const int lane = tid & 63;
    const int wr   = wave >> 2;       // 2 M-rows of waves
    const int wc   = wave & 3;        // 4 N-cols of waves
    const int l15  = lane & 15;
    const int lq   = lane >> 4;
    const int l7   = lane & 7;

    // XCD-aware bijective swizzle (nwg = 512, % 8 == 0)
    const int nwg = gridDim.x;
    const int cpx = nwg >> 3;
    const int wg  = blockIdx.x;
    const int swz = (wg & 7) * cpx + (wg >> 3);
    const int bm  = swz >> 4;         // 16 n-tiles (4096/256)
    const int bn  = swz & 15;
    const int m0  = bm * 256;
    const int n0  = bn * 256;

    f32x4 acc[8][4];
#pragma unroll
    for (int m = 0; m < 8; ++m)
#pragma unroll
        for (int n = 0; n < 4; ++n) acc[m][n] = (f32x4){0.f, 0.f, 0.f, 0.f};

    bf16x8 af0[4][2], af1[4][2], bfr[2][2];

    // ---- prologue: tile0 (A+B) and tile1 (A only); 12 loads in flight
    stage_half(A + (size_t)m0 * IN_F,                sm + 0,     wave, lane);  // A(0) h0
    stage_half(A + (size_t)(m0 + 128) * IN_F,        sm + 16384, wave, lane);  // A(0) h1
    stage_half(B + (size_t)n0 * IN_F,                sm + 32768, wave, lane);  // B(0) h0
    stage_half(B + (size_t)(n0 + 128) * IN_F,        sm + 49152, wave, lane);  // B(0) h1
    stage_half(A + (size_t)m0 * IN_F + 64,           sm + 65536, wave, lane);  // A(1) h0
    stage_half(A + (size_t)(m0 + 128) * IN_F + 64,   sm + 81920, wave, lane);  // A(1) h1
    VMCNT4();          // tile0 fully landed; A(1) may still be in flight
    BARRIER();

    for (int i = 0; i < 32; ++i) {
        const int tB1 = 2 * i + 1;                 // B of odd tile (buf1) staged P1/P2
        const int t2  = 2 * i + 2;                 // even tile (buf0) staged P3..P6
        const int t3  = 2 * i + 3;                 // odd tile A (buf1) staged P7/P8
        const bool g2 = t2 < NKT;
        const bool g3 = t3 < NKT;
        const bf16* Bk1 = B + (size_t)tB1 * 64;
        const bf16* Ak2 = A + (size_t)t2 * 64;
        const bf16* Bk2 = B + (size_t)t2 * 64;
        const bf16* Ak3 = A + (size_t)t3 * 64;

        // ---- P1: compute t0 quadrant (mh0, nh0)
        LDA_SET(af0, 0, 0);
        LDB_SET(0, 0);
        stage_half(Bk1 + (size_t)n0 * IN_F,         sm + 98304,  wave, lane);  // B(t0+1) h0
        BARRIER(); LGKM0();
        MMA_Q(af0, 0, 0);
        BARRIER();
        // ---- P2: (mh1, nh0)
        LDA_SET(af1, 0, 1);
        stage_half(Bk1 + (size_t)(n0 + 128) * IN_F, sm + 114688, wave, lane);  // B(t0+1) h1
        BARRIER(); LGKM0();
        MMA_Q(af1, 1, 0);
        BARRIER();
        // ---- P3: (mh0, nh1)   [A(t0) reads finished at P2 -> safe to restage buf0.A]
        LDB_SET(0, 1);
        if (g2) stage_half(Ak2 + (size_t)m0 * IN_F,         sm + 0,     wave, lane);
        BARRIER(); LGKM0();
        MMA_Q(af0, 0, 1);
        BARRIER();
        // ---- P4: (mh1, nh1)
        if (g2) stage_half(Ak2 + (size_t)(m0 + 128) * IN_F, sm + 16384, wave, lane);
        BARRIER(); LGKM0();
        MMA_Q(af1, 1, 1);
        if (i < 31) { VMCNT4(); } else { VMCNT0(); }   // tile t0+1 fully landed
        BARRIER();

        // ---- P5: compute t0+1 (buf1) quadrant (mh0, nh0)  [B(t0) reads done at P4]
        LDA_SET(af0, 1, 0);
        LDB_SET(1, 0);
        if (g2) stage_half(Bk2 + (size_t)n0 * IN_F,         sm + 32768, wave, lane);
        BARRIER(); LGKM0();
        MMA_Q(af0, 0, 0);
        BARRIER();
        // ---- P6: (mh1, nh0)
        LDA_SET(af1, 1, 1);
        if (g2) stage_half(Bk2 + (size_t)(n0 + 128) * IN_F, sm + 49152, wave, lane);
        BARRIER(); LGKM0();
        MMA_Q(af1, 1, 0);
        BARRIER();
        // ---- P7: (mh0, nh1)   [A(t0+1) reads finished at P6]
        LDB_SET(1, 1);
        if (g3) stage_half(Ak3 + (size_t)m0 * IN_F,         sm + 65536, wave, lane);
        BARRIER(); LGKM0();
        MMA_Q(af0, 0, 1);
        BARRIER();
        // ---- P8: (mh1, nh1)
        if (g3) stage_half(Ak3 + (size_t)(m0 + 128) * IN_F, sm + 81920, wave, lane);
        BARRIER(); LGKM0();
        MMA_Q(af1, 1, 1);
        if (i < 31) { VMCNT4(); } else { VMCNT0(); }   // tile t0+2 fully landed
        BARRIER();
    }

    // ---- epilogue: C/D layout col = lane&15, row = (lane>>4)*4 + reg
    const int crow0 = m0 + wr * 128 + lq * 4;
    const int ccol0 = n0 + wc * 64 + l15;
#pragma unroll
    for (int n = 0; n < 4; ++n) {
        float bv = bias[ccol0 + n * 16];
#pragma unroll
        for (int m = 0; m < 8; ++m)
#pragma unroll
            for (int r = 0; r < 4; ++r)
                C[(size_t)(crow0 + m * 16 + r) * OUT_F + ccol0 + n * 16] = acc[m][n][r] + bv;
    }
}

// ---------------- fallback: fp32 tiled GEMM with on-the-fly dequant (ws too small)
__global__ __launch_bounds__(256) void fallback_gemm(const float* __restrict__ x,
                                                     const int* __restrict__ qweight,
                                                     const float* __restrict__ scales,
                                                     const int* __restrict__ qzeros,
                                                     const float* __restrict__ bias,
                                                     float* __restrict__ out) {
    __shared__ float Asf[64][65];
    __shared__ float Bsf[64][65];
    int bm = blockIdx.x >> 6;
    int bn = blockIdx.x & 63;
    int m0 = bm * 64, n0 = bn * 64;
    int t  = threadIdx.x;
    int tr = t >> 4, tc = t & 15;
    float acc[4][4] = {};
    for (int kt = 0; kt < IN_F; kt += 64) {
#pragma unroll
        for (int i = 0; i < 4; ++i) {
            int idx = t + i * 256;
            int r = idx >> 4, c4 = idx & 15;
            float4 v = *reinterpret_cast<const float4*>(x + (size_t)(m0 + r) * IN_F + kt + c4 * 4);
            Asf[r][c4 * 4 + 0] = v.x; Asf[r][c4 * 4 + 1] = v.y;
            Asf[r][c4 * 4 + 2] = v.z; Asf[r][c4 * 4 + 3] = v.w;
        }
#pragma unroll
        for (int i = 0; i < 2; ++i) {
            int idx = t + i * 256;
            int r = idx >> 3, k8 = idx & 7;
            int kk = kt + k8 * 8;
            int o  = n0 + r;
            int qw = qweight[(size_t)o * (IN_F / 8) + (kk >> 3)];
            int g  = kk >> 7;
            float s = scales[g * OUT_F + o];
            float z = (float)qzeros[g * OUT_F + o];
#pragma unroll
            for (int b = 0; b < 8; ++b)
                Bsf[r][k8 * 8 + b] = ((float)((qw >> (4 * b)) & 15) - z) * s;
        }
        __syncthreads();
#pragma unroll 8
        for (int k = 0; k < 64; ++k) {
            float a[4], bb[4];
#pragma unroll
            for (int i = 0; i < 4; ++i) a[i] = Asf[tr * 4 + i][k];
#pragma unroll
            for (int j = 0; j < 4; ++j) bb[j] = Bsf[tc * 4 + j][k];
#pragma unroll
            for (int i = 0; i < 4; ++i)
#pragma unroll
                for (int j = 0; j < 4; ++j) acc[i][j] += a[i] * bb[j];
        }
        __syncthreads();
    }
#pragma unroll
    for (int i = 0; i < 4; ++i) {
        int row = m0 + tr * 4 + i;
#pragma unroll
        for (int j = 0; j < 4; ++j) {
            int col = n0 + tc * 4 + j;
            out[(size_t)row * OUT_F + col] = acc[i][j] + bias[col];
        }
    }
}

extern "C" void kernel_launch(void* const* d_in, const int* in_sizes, int n_in,
                              void* d_out, int out_size, void* d_ws, size_t ws_size,
                              hipStream_t stream) {
    (void)in_sizes; (void)n_in; (void)out_size;
    const float* x       = (const float*)d_in[0];
    const int*   qweight = (const int*)d_in[1];
    const float* scales  = (const float*)d_in[2];
    const int*   qzeros  = (const int*)d_in[3];
    const float* bias    = (const float*)d_in[4];
    float* out = (float*)d_out;

    const size_t needW = (size_t)OUT_F * IN_F * sizeof(bf16);   // 32 MB
    const size_t needX = (size_t)M_TOTAL * IN_F * sizeof(bf16); // 64 MB

    if (ws_size >= needW + needX) {
        bf16* Wb = (bf16*)d_ws;
        bf16* Xb = (bf16*)((char*)d_ws + needW);
        dequant_w<<<(OUT_F * (IN_F / 8)) / 256, 256, 0, stream>>>(qweight, scales, qzeros, Wb);
        int n8 = M_TOTAL * IN_F / 8;
        cvt_x<<<(n8 + 255) / 256, 256, 0, stream>>>(x, Xb, n8);
        gemm256<<<(M_TOTAL / 256) * (OUT_F / 256), 512, 131072, stream>>>(Xb, Wb, bias, out);
    } else {
        fallback_gemm<<<(M_TOTAL / 64) * (OUT_F / 64), 256, 0, stream>>>(
            x, qweight, scales, qzeros, bias, out);
    }
}